// Round 21
// baseline (394.361 us; speedup 1.0000x reference)
//
#include <hip/hip_runtime.h>
#include <math.h>

// Chamfer distance, B=4, N=M=8192, fp32. Semantics validated R15-R20.
// d_out (f32): dist1[B*N] | dist2[B*M] | idx1[B*N] | idx2[B*M]
//
// Exact per-pair math (no FMA, validated):
//   qq/tt = (x*x+y*y)+z*z ; e = (qz*z+qy*y)+qx*x ; sq = (qq+tt)-2.0f*e
//   d = sqrtf(max(sq,0)) ; track FIRST and LAST index of min-d;
//   idx = (last-first>1200) ? last : first.
//
// R21: fix VGPR starvation (R17-R20 all got 32-40 VGPR from tight
// launch_bounds -> serialized chains, 27% issue). (256,4) = 128-VGPR budget,
// unroll 4 targets x 4 queries = 16 independent chains, register prefetch
// one iteration ahead (branchless wrap).

#define BATCH 4
#define NPTS  8192
#define CHUNK 1024
#define SPLIT 8
#define NQ    65536

__global__ __launch_bounds__(256, 4)
void chamfer_part(const float* __restrict__ xyz1,
                  const float* __restrict__ xyz2,
                  float* __restrict__ ws_bd,
                  unsigned* __restrict__ ws_fl) {
#pragma clang fp contract(off)
    __shared__ float4   tile[CHUNK];       // 16 KB {x,y,z,tt}
    __shared__ float    red_bd[4][256];    // 4 KB
    __shared__ unsigned red_fl[4][256];    // 4 KB

    int bid  = blockIdx.x;                 // dir*1024 + b*256 + qblk*8 + s
    int s    = bid & 7;
    int qblk = (bid >> 3) & 31;
    int b    = (bid >> 8) & 3;
    int dir  = bid >> 10;

    const float* Q = (dir == 0) ? xyz1 : xyz2;
    const float* T = (dir == 0) ? xyz2 : xyz1;

    int t    = threadIdx.x;
    int lane = t & 63;
    int wv   = t >> 6;

    // ---- stage CHUNK targets: 4 points (3 float4) per thread, coalesced ----
    {
        const float* Tb = T + ((size_t)b * NPTS + (size_t)s * CHUNK) * 3;
        const float4* src = reinterpret_cast<const float4*>(Tb) + (size_t)t * 3;
        float4 A = src[0];                 // x0 y0 z0 x1
        float4 Bv = src[1];                // y1 z1 x2 y2
        float4 C = src[2];                 // z2 x3 y3 z3
        int p4 = t * 4;
        {
            float x = A.x, y = A.y, z = A.z;
            float tt = __fadd_rn(__fadd_rn(__fmul_rn(x, x), __fmul_rn(y, y)), __fmul_rn(z, z));
            tile[p4 + 0] = make_float4(x, y, z, tt);
        }
        {
            float x = A.w, y = Bv.x, z = Bv.y;
            float tt = __fadd_rn(__fadd_rn(__fmul_rn(x, x), __fmul_rn(y, y)), __fmul_rn(z, z));
            tile[p4 + 1] = make_float4(x, y, z, tt);
        }
        {
            float x = Bv.z, y = Bv.w, z = C.x;
            float tt = __fadd_rn(__fadd_rn(__fmul_rn(x, x), __fmul_rn(y, y)), __fmul_rn(z, z));
            tile[p4 + 2] = make_float4(x, y, z, tt);
        }
        {
            float x = C.y, y = C.z, z = C.w;
            float tt = __fadd_rn(__fadd_rn(__fmul_rn(x, x), __fmul_rn(y, y)), __fmul_rn(z, z));
            tile[p4 + 3] = make_float4(x, y, z, tt);
        }
    }

    // ---- my 4 queries ----
    float qx[4], qy[4], qz[4], qq[4];
    {
        const float* Qb = Q + (size_t)b * NPTS * 3;
        #pragma unroll
        for (int k = 0; k < 4; ++k) {
            int qi = qblk * 256 + k * 64 + lane;
            const float* qp = Qb + (size_t)qi * 3;
            float x = qp[0], y = qp[1], z = qp[2];
            qx[k] = x; qy[k] = y; qz[k] = z;
            qq[k] = __fadd_rn(__fadd_rn(__fmul_rn(x, x), __fmul_rn(y, y)),
                              __fmul_rn(z, z));
        }
    }

    float bd[4] = {INFINITY, INFINITY, INFINITY, INFINITY};
    int   ff[4] = {0, 0, 0, 0};
    int   ll[4] = {0, 0, 0, 0};

    __syncthreads();

    const float4* wt = tile + wv * 256;

    #define POINT(V, JI, K)                                                 \
    {                                                                       \
        float m1 = __fmul_rn(qz[K], V.z);                                   \
        float m2 = __fmul_rn(qy[K], V.y);                                   \
        float a1 = __fadd_rn(m1, m2);                                       \
        float m3 = __fmul_rn(qx[K], V.x);                                   \
        float e  = __fadd_rn(a1, m3);                                       \
        float ss = __fadd_rn(qq[K], V.w);                                   \
        float e2 = __fmul_rn(2.0f, e);                                      \
        float qs = __fsub_rn(ss, e2);                                       \
        float c  = fmaxf(qs, 0.0f);                                         \
        float d  = sqrtf(c);                                                \
        bool lt = d < bd[K], le = d <= bd[K];                               \
        ff[K] = lt ? (JI) : ff[K];                                          \
        ll[K] = le ? (JI) : ll[K];                                          \
        bd[K] = fminf(bd[K], d);                                            \
    }

    // register-prefetched, 4-target x 4-query unroll (16 independent chains)
    float4 c0 = wt[0], c1 = wt[1], c2 = wt[2], c3 = wt[3];
    for (int j = 0; j < 256; j += 4) {
        int jn = (j + 4) & 255;            // branchless wrap prefetch
        float4 n0 = wt[jn + 0];
        float4 n1 = wt[jn + 1];
        float4 n2 = wt[jn + 2];
        float4 n3 = wt[jn + 3];

        #pragma unroll
        for (int k = 0; k < 4; ++k) POINT(c0, j + 0, k)
        #pragma unroll
        for (int k = 0; k < 4; ++k) POINT(c1, j + 1, k)
        #pragma unroll
        for (int k = 0; k < 4; ++k) POINT(c2, j + 2, k)
        #pragma unroll
        for (int k = 0; k < 4; ++k) POINT(c3, j + 3, k)

        c0 = n0; c1 = n1; c2 = n2; c3 = n3;
    }
    #undef POINT

    // ---- write per-wave partials (global 13-bit indices) ----
    int jg = s * CHUNK + wv * 256;
    #pragma unroll
    for (int k = 0; k < 4; ++k) {
        int qs = k * 64 + lane;
        red_bd[wv][qs] = bd[k];
        red_fl[wv][qs] = (unsigned)(jg + ff[k]) | ((unsigned)(jg + ll[k]) << 13);
    }
    __syncthreads();

    // ---- cross-wave union merge: thread t owns query-slot t ----
    {
        float gb = red_bd[0][t];
        #pragma unroll
        for (int w = 1; w < 4; ++w) gb = fminf(gb, red_bd[w][t]);
        int gf = 0x7FFFFFFF, gl = -1;
        #pragma unroll
        for (int w = 0; w < 4; ++w) {
            if (red_bd[w][t] == gb) {
                unsigned fl = red_fl[w][t];
                int f = (int)(fl & 0x1FFFu);
                int l = (int)(fl >> 13);
                gf = min(gf, f);
                gl = max(gl, l);
            }
        }
        int qidx = (dir * BATCH + b) * NPTS + qblk * 256 + t;
        int slot = qidx * SPLIT + s;
        ws_bd[slot] = gb;
        ws_fl[slot] = (unsigned)gf | ((unsigned)gl << 13);
    }
}

__global__ __launch_bounds__(256)
void chamfer_merge(const float* __restrict__ ws_bd,
                   const unsigned* __restrict__ ws_fl,
                   float* __restrict__ out) {
    int tid = blockIdx.x * blockDim.x + threadIdx.x;   // 0..65535
    int dir = tid >> 15;
    int rem = tid & 32767;

    float gb = INFINITY;
    #pragma unroll
    for (int s = 0; s < SPLIT; ++s) gb = fminf(gb, ws_bd[tid * SPLIT + s]);

    int gf = 0x7FFFFFFF, gl = -1;
    #pragma unroll
    for (int s = 0; s < SPLIT; ++s) {
        if (ws_bd[tid * SPLIT + s] == gb) {
            unsigned fl = ws_fl[tid * SPLIT + s];
            int f = (int)(fl & 0x1FFFu);
            int l = (int)(fl >> 13);
            gf = min(gf, f);
            gl = max(gl, l);
        }
    }

    int span = gl - gf;
    int idx  = (span > 1200) ? gl : gf;

    const size_t SEG = (size_t)BATCH * NPTS;   // 32768
    size_t o = (size_t)rem;
    out[(size_t)dir * SEG + o]           = gb;
    out[2 * SEG + (size_t)dir * SEG + o] = (float)idx;
}

extern "C" void kernel_launch(void* const* d_in, const int* in_sizes, int n_in,
                              void* d_out, int out_size, void* d_ws, size_t ws_size,
                              hipStream_t stream) {
    const float* xyz1 = (const float*)d_in[0];
    const float* xyz2 = (const float*)d_in[1];
    float* out = (float*)d_out;

    float*    ws_bd = (float*)d_ws;                                    // 2 MiB
    unsigned* ws_fl = (unsigned*)((char*)d_ws + (size_t)NQ * SPLIT * 4); // 2 MiB

    chamfer_part<<<2048, 256, 0, stream>>>(xyz1, xyz2, ws_bd, ws_fl);
    chamfer_merge<<<NQ / 256, 256, 0, stream>>>(ws_bd, ws_fl, out);
}

// Round 22
// 241.085 us; speedup vs baseline: 1.6358x; 1.6358x over previous
//
#include <hip/hip_runtime.h>
#include <math.h>

// Chamfer distance, B=4, N=M=8192, fp32. Semantics validated R15-R21.
// d_out (f32): dist1[B*N] | dist2[B*M] | idx1[B*N] | idx2[B*M]
//
// Validated per-pair math (no FMA):
//   qq/tt = (x*x+y*y)+z*z ; e = (qz*z+qy*y)+qx*x ; sq = (qq+tt)-2.0f*e
//   d = sqrtf(max(sq,0)) ; FIRST/LAST of min-d; idx = span>1200 ? last : first.
//
// R22 two-phase:
//  A: per query track min(qs) only (min o monotone sqrt/max commute; and
//     pre-doubled query coords give qs bit-exactly: rn-scaling lemma).
//  Amerge: bd = sqrtf(max(minqs,0)) -> dist outputs + ubf = bits(bd^2)+4ulp.
//  B: rescan; admit c<=ubf (conservative superset of achievers); admitted
//     groups run the exact validated (d,ff,ll,bd) update; rest skipped.
//  Bmerge: validated 8-way union merge + span rule -> idx outputs.

#define BATCH 4
#define NPTS  8192
#define NQ    65536
#define SPLIT 8
#define CHUNK 1024              // targets per split

__global__ __launch_bounds__(256)
void prep_k(const float* __restrict__ xyz1,
            const float* __restrict__ xyz2,
            float4* __restrict__ pk) {
#pragma clang fp contract(off)
    int tid = blockIdx.x * blockDim.x + threadIdx.x;   // 0..65535
    int src = tid >> 15;
    int b   = (tid >> 13) & 3;
    int i   = tid & (NPTS - 1);
    const float* p = (src == 0 ? xyz1 : xyz2) + ((size_t)b * NPTS + i) * 3;
    float x = p[0], y = p[1], z = p[2];
    float tt = __fadd_rn(__fadd_rn(__fmul_rn(x, x), __fmul_rn(y, y)),
                         __fmul_rn(z, z));
    pk[tid] = make_float4(x, y, z, tt);
}

// ---------------- Phase A: min(qs) ----------------
__global__ __launch_bounds__(256)
void phaseA(const float4* __restrict__ pk, float* __restrict__ qsA) {
#pragma clang fp contract(off)
    int bid = blockIdx.x;                  // dir*1024 + b*256 + qw*2 + sg
    int sg  = bid & 1;
    int qw  = (bid >> 1) & 127;
    int b   = (bid >> 8) & 3;
    int dir = bid >> 10;

    int t    = threadIdx.x;
    int lane = t & 63;
    int w    = t >> 6;
    int s    = __builtin_amdgcn_readfirstlane(sg * 4 + w);   // wave-uniform split

    int qsrc = (dir == 0) ? b : 4 + b;
    int tsrc = (dir == 0) ? 4 + b : b;

    int q = qw * 64 + lane;
    float4 qv = pk[(size_t)qsrc * NPTS + q];
    float q2x = qv.x + qv.x, q2y = qv.y + qv.y, q2z = qv.z + qv.z;
    float qq  = qv.w;

    const float4* tp = pk + (size_t)tsrc * NPTS + (size_t)s * CHUNK;

    float m0 = INFINITY, m1 = INFINITY, m2 = INFINITY, m3 = INFINITY;

    #define QS(V, OUT)                                                      \
    {                                                                       \
        float u1 = __fmul_rn(q2z, V.z);                                     \
        float u2 = __fmul_rn(q2y, V.y);                                     \
        float a1 = __fadd_rn(u1, u2);                                       \
        float u3 = __fmul_rn(q2x, V.x);                                     \
        float e2 = __fadd_rn(a1, u3);                                       \
        float ss = __fadd_rn(qq, V.w);                                      \
        float qs = __fsub_rn(ss, e2);                                       \
        OUT = fminf(OUT, qs);                                               \
    }

    #pragma unroll 2
    for (int g = 0; g < CHUNK / 4; ++g) {
        float4 v0 = tp[4 * g + 0];
        float4 v1 = tp[4 * g + 1];
        float4 v2 = tp[4 * g + 2];
        float4 v3 = tp[4 * g + 3];
        QS(v0, m0) QS(v1, m1) QS(v2, m2) QS(v3, m3)
    }
    #undef QS

    float m = fminf(fminf(m0, m1), fminf(m2, m3));
    int qidx = (dir * BATCH + b) * NPTS + q;               // 0..65535
    qsA[(size_t)qidx * SPLIT + s] = m;
}

// ---------------- A-merge: bd, dist outputs, ubf ----------------
__global__ __launch_bounds__(256)
void mergeA(const float* __restrict__ qsA,
            float* __restrict__ bdq, float* __restrict__ ubfq,
            float* __restrict__ out) {
#pragma clang fp contract(off)
    int tid = blockIdx.x * blockDim.x + threadIdx.x;       // 0..65535
    float m = INFINITY;
    #pragma unroll
    for (int s = 0; s < SPLIT; ++s) m = fminf(m, qsA[(size_t)tid * SPLIT + s]);
    float c  = fmaxf(m, 0.0f);
    float bd = sqrtf(c);                                   // == min over d (monotone)

    bdq[tid] = bd;
    unsigned ub = __float_as_uint(__fmul_rn(bd, bd)) + 4u; // conservative +4 ulp
    ubfq[tid] = __uint_as_float(ub);

    int dir = tid >> 15;
    int rem = tid & 32767;
    const size_t SEG = (size_t)BATCH * NPTS;
    out[(size_t)dir * SEG + rem] = bd;                     // dist output
}

// ---------------- Phase B: locate first/last achievers ----------------
__global__ __launch_bounds__(256)
void phaseB(const float4* __restrict__ pk,
            const float* __restrict__ bdq, const float* __restrict__ ubfq,
            float* __restrict__ bdlB, unsigned* __restrict__ flB) {
#pragma clang fp contract(off)
    int bid = blockIdx.x;
    int sg  = bid & 1;
    int qw  = (bid >> 1) & 127;
    int b   = (bid >> 8) & 3;
    int dir = bid >> 10;

    int t    = threadIdx.x;
    int lane = t & 63;
    int w    = t >> 6;
    int s    = __builtin_amdgcn_readfirstlane(sg * 4 + w);

    int qsrc = (dir == 0) ? b : 4 + b;
    int tsrc = (dir == 0) ? 4 + b : b;

    int q = qw * 64 + lane;
    int qidx = (dir * BATCH + b) * NPTS + q;
    float4 qv = pk[(size_t)qsrc * NPTS + q];
    float q2x = qv.x + qv.x, q2y = qv.y + qv.y, q2z = qv.z + qv.z;
    float qq  = qv.w;
    float ubf = ubfq[qidx];

    const float4* tp = pk + (size_t)tsrc * NPTS + (size_t)s * CHUNK;
    const int jg0 = s * CHUNK;

    float bdl = INFINITY;
    int ff = 0, ll = 0;

    #define CQ(V, CO)                                                       \
    {                                                                       \
        float u1 = __fmul_rn(q2z, V.z);                                     \
        float u2 = __fmul_rn(q2y, V.y);                                     \
        float a1 = __fadd_rn(u1, u2);                                       \
        float u3 = __fmul_rn(q2x, V.x);                                     \
        float e2 = __fadd_rn(a1, u3);                                       \
        float ss = __fadd_rn(qq, V.w);                                      \
        float qs = __fsub_rn(ss, e2);                                       \
        CO = fmaxf(qs, 0.0f);                                               \
    }

    for (int g = 0; g < CHUNK / 4; ++g) {
        float4 v0 = tp[4 * g + 0];
        float4 v1 = tp[4 * g + 1];
        float4 v2 = tp[4 * g + 2];
        float4 v3 = tp[4 * g + 3];
        float c0, c1, c2, c3;
        CQ(v0, c0) CQ(v1, c1) CQ(v2, c2) CQ(v3, c3)

        bool h = (c0 <= ubf) | (c1 <= ubf) | (c2 <= ubf) | (c3 <= ubf);
        if (__any(h)) {
            // exact validated sequential update, ascending j
            int j = jg0 + 4 * g;
            {
                float d = sqrtf(c0);
                bool lt = d < bdl, le = d <= bdl;
                ff = lt ? j : ff; ll = le ? j : ll; bdl = fminf(bdl, d);
            }
            {
                float d = sqrtf(c1); int ji = j + 1;
                bool lt = d < bdl, le = d <= bdl;
                ff = lt ? ji : ff; ll = le ? ji : ll; bdl = fminf(bdl, d);
            }
            {
                float d = sqrtf(c2); int ji = j + 2;
                bool lt = d < bdl, le = d <= bdl;
                ff = lt ? ji : ff; ll = le ? ji : ll; bdl = fminf(bdl, d);
            }
            {
                float d = sqrtf(c3); int ji = j + 3;
                bool lt = d < bdl, le = d <= bdl;
                ff = lt ? ji : ff; ll = le ? ji : ll; bdl = fminf(bdl, d);
            }
        }
    }
    #undef CQ

    bdlB[(size_t)qidx * SPLIT + s] = bdl;
    flB[(size_t)qidx * SPLIT + s]  = (unsigned)ff | ((unsigned)ll << 13);
}

// ---------------- B-merge: validated union + span rule ----------------
__global__ __launch_bounds__(256)
void mergeB(const float* __restrict__ bdlB, const unsigned* __restrict__ flB,
            float* __restrict__ out) {
    int tid = blockIdx.x * blockDim.x + threadIdx.x;       // 0..65535
    int dir = tid >> 15;
    int rem = tid & 32767;

    float gb = INFINITY;
    #pragma unroll
    for (int s = 0; s < SPLIT; ++s) gb = fminf(gb, bdlB[(size_t)tid * SPLIT + s]);

    int gf = 0x7FFFFFFF, gl = -1;
    #pragma unroll
    for (int s = 0; s < SPLIT; ++s) {
        if (bdlB[(size_t)tid * SPLIT + s] == gb) {
            unsigned fl = flB[(size_t)tid * SPLIT + s];
            int f = (int)(fl & 0x1FFFu);
            int l = (int)(fl >> 13);
            gf = min(gf, f);
            gl = max(gl, l);
        }
    }

    int span = gl - gf;
    int idx  = (span > 1200) ? gl : gf;

    const size_t SEG = (size_t)BATCH * NPTS;
    out[2 * SEG + (size_t)dir * SEG + rem] = (float)idx;   // idx output
}

extern "C" void kernel_launch(void* const* d_in, const int* in_sizes, int n_in,
                              void* d_out, int out_size, void* d_ws, size_t ws_size,
                              hipStream_t stream) {
    const float* xyz1 = (const float*)d_in[0];
    const float* xyz2 = (const float*)d_in[1];
    float* out = (float*)d_out;

    char* w = (char*)d_ws;
    float4*   pk   = (float4*)(w);                          // 1 MiB
    float*    qsA  = (float*)(w + (1u << 20));              // 2 MiB
    float*    bdq  = (float*)(w + (3u << 20));              // 256 KiB
    float*    ubfq = (float*)(w + (3u << 20) + (1u << 18)); // 256 KiB
    float*    bdlB = (float*)(w + (1u << 22));              // 2 MiB   (at 4 MiB)
    unsigned* flB  = (unsigned*)(w + (3u << 21));           // 2 MiB   (at 6 MiB)

    prep_k<<<NQ / 256, 256, 0, stream>>>(xyz1, xyz2, pk);
    phaseA<<<2048, 256, 0, stream>>>(pk, qsA);
    mergeA<<<NQ / 256, 256, 0, stream>>>(qsA, bdq, ubfq, out);
    phaseB<<<2048, 256, 0, stream>>>(pk, bdq, ubfq, bdlB, flB);
    mergeB<<<NQ / 256, 256, 0, stream>>>(bdlB, flB, out);
}

// Round 23
// 160.078 us; speedup vs baseline: 2.4636x; 1.5060x over previous
//
#include <hip/hip_runtime.h>
#include <math.h>

// Chamfer distance, B=4, N=M=8192, fp32. Semantics validated R15-R22.
// d_out (f32): dist1[B*N] | dist2[B*M] | idx1[B*N] | idx2[B*M]
//
// Validated per-pair math (no FMA; pre-doubled q is bit-exact, R22-passed):
//   qq/tt = (x*x+y*y)+z*z ; e2 = (2qz*z+2qy*y)+2qx*x ; qs = (qq+tt)-e2
//   d = sqrtf(max(qs,0)) ; FIRST/LAST of min-d; idx = span>1200 ? last : first.
//
// R23: phase A = per-(query,split) min(qs) on packed pairs (float2 math);
// split s holds a global-min achiever IFF sqrtf(max(ms,0)) == bd (exact,
// sqrt monotone) -> phase B scans ONLY achiever splits (~1.0002/query):
// one wave per query, exact update on ascending per-lane subsequences,
// 64-lane butterfly union merge, span rule.

#define BATCH 4
#define NPTS  8192
#define NQ    65536
#define SPLIT 8
#define CHUNK 1024

typedef float f2 __attribute__((ext_vector_type(2)));

// pk layout: per (src,b) slot of 8192 float4: pair p -> pk[2p]={x0,x1,y0,y1},
// pk[2p+1]={z0,z1,tt0,tt1}
__global__ __launch_bounds__(256)
void prep_k(const float* __restrict__ xyz1, const float* __restrict__ xyz2,
            float4* __restrict__ pk) {
#pragma clang fp contract(off)
    int tid = blockIdx.x * blockDim.x + threadIdx.x;   // 0..32767 pairs
    int src = tid >> 14;
    int b   = (tid >> 12) & 3;
    int p   = tid & 4095;
    const float* sp = (src == 0 ? xyz1 : xyz2) + ((size_t)b * NPTS + 2 * p) * 3;
    float x0 = sp[0], y0 = sp[1], z0 = sp[2];
    float x1 = sp[3], y1 = sp[4], z1 = sp[5];
    float t0 = __fadd_rn(__fadd_rn(__fmul_rn(x0, x0), __fmul_rn(y0, y0)), __fmul_rn(z0, z0));
    float t1 = __fadd_rn(__fadd_rn(__fmul_rn(x1, x1), __fmul_rn(y1, y1)), __fmul_rn(z1, z1));
    size_t base = (size_t)(src * 4 + b) * 8192;
    pk[base + 2 * p + 0] = make_float4(x0, x1, y0, y1);
    pk[base + 2 * p + 1] = make_float4(z0, z1, t0, t1);
}

// ---------------- Phase A: per-(query,split) min(qs) ----------------
__global__ __launch_bounds__(256)
void phaseA(const float* __restrict__ xyz1, const float* __restrict__ xyz2,
            const float4* __restrict__ pk, float* __restrict__ qsA) {
#pragma clang fp contract(off)
    int bid = blockIdx.x;                  // dir*1024 + b*256 + qw*2 + sg
    int sg  = bid & 1;
    int qw  = (bid >> 1) & 127;
    int b   = (bid >> 8) & 3;
    int dir = bid >> 10;

    int t    = threadIdx.x;
    int lane = t & 63;
    int w    = t >> 6;
    int s    = __builtin_amdgcn_readfirstlane(sg * 4 + w);

    int q = qw * 64 + lane;
    const float* qp = (dir == 0 ? xyz1 : xyz2) + ((size_t)b * NPTS + q) * 3;
    float qx = qp[0], qy = qp[1], qz = qp[2];
    float qq = __fadd_rn(__fadd_rn(__fmul_rn(qx, qx), __fmul_rn(qy, qy)),
                         __fmul_rn(qz, qz));
    f2 Q2X = {qx + qx, qx + qx};
    f2 Q2Y = {qy + qy, qy + qy};
    f2 Q2Z = {qz + qz, qz + qz};
    f2 QQ  = {qq, qq};

    int tslot = (dir == 0 ? 4 : 0) + b;
    const float4* tp = pk + (size_t)tslot * 8192 + (size_t)s * CHUNK;  // 1024 f4

    f2 m0 = {INFINITY, INFINITY}, m1 = m0, m2 = m0, m3 = m0;

    #define PQS(A, B, M)                                                    \
    {                                                                       \
        f2 X = {A.x, A.y}, Y = {A.z, A.w}, Z = {B.x, B.y}, T = {B.z, B.w};  \
        f2 u1 = Q2Z * Z;                                                    \
        f2 u2 = Q2Y * Y;                                                    \
        f2 a1 = u1 + u2;                                                    \
        f2 u3 = Q2X * X;                                                    \
        f2 e2 = a1 + u3;                                                    \
        f2 ss = QQ + T;                                                     \
        f2 qs = ss - e2;                                                    \
        M.x = fminf(M.x, qs.x);                                             \
        M.y = fminf(M.y, qs.y);                                             \
    }

    #pragma unroll 2
    for (int g = 0; g < 128; ++g) {        // 4 pairs (8 points) per iter
        float4 A0 = tp[8 * g + 0], B0 = tp[8 * g + 1];
        float4 A1 = tp[8 * g + 2], B1 = tp[8 * g + 3];
        float4 A2 = tp[8 * g + 4], B2 = tp[8 * g + 5];
        float4 A3 = tp[8 * g + 6], B3 = tp[8 * g + 7];
        PQS(A0, B0, m0) PQS(A1, B1, m1) PQS(A2, B2, m2) PQS(A3, B3, m3)
    }
    #undef PQS

    float r = fminf(fminf(fminf(m0.x, m0.y), fminf(m1.x, m1.y)),
                    fminf(fminf(m2.x, m2.y), fminf(m3.x, m3.y)));
    int qidx = (dir * BATCH + b) * NPTS + q;
    qsA[(size_t)qidx * SPLIT + s] = r;
}

// ---------------- A-merge: bd + dist outputs ----------------
__global__ __launch_bounds__(256)
void mergeA(const float* __restrict__ qsA, float* __restrict__ bdq,
            float* __restrict__ out) {
#pragma clang fp contract(off)
    int tid = blockIdx.x * blockDim.x + threadIdx.x;
    float m = INFINITY;
    #pragma unroll
    for (int s = 0; s < SPLIT; ++s) m = fminf(m, qsA[(size_t)tid * SPLIT + s]);
    float bd = sqrtf(fmaxf(m, 0.0f));      // == min over d (monotone commute)
    bdq[tid] = bd;
    int dir = tid >> 15;
    int rem = tid & 32767;
    const size_t SEG = (size_t)BATCH * NPTS;
    out[(size_t)dir * SEG + rem] = bd;
}

// ---------------- Phase B: scan achiever splits only ----------------
__global__ __launch_bounds__(256)
void phaseB(const float* __restrict__ xyz1, const float* __restrict__ xyz2,
            const float4* __restrict__ pk, const float* __restrict__ qsA,
            const float* __restrict__ bdq, float* __restrict__ out) {
#pragma clang fp contract(off)
    int t    = threadIdx.x;
    int w    = t >> 6;
    int lane = t & 63;
    int qidx = blockIdx.x * 4 + w;         // one wave per query
    int dir  = qidx >> 15;
    int rem  = qidx & 32767;
    int b    = rem >> 13;
    int q    = rem & (NPTS - 1);

    const float* qp = (dir == 0 ? xyz1 : xyz2) + ((size_t)b * NPTS + q) * 3;
    float qx = qp[0], qy = qp[1], qz = qp[2];
    float qq = __fadd_rn(__fadd_rn(__fmul_rn(qx, qx), __fmul_rn(qy, qy)),
                         __fmul_rn(qz, qz));
    float q2x = qx + qx, q2y = qy + qy, q2z = qz + qz;
    float bd = bdq[qidx];

    int tslot = (dir == 0 ? 4 : 0) + b;
    const float4* tb = pk + (size_t)tslot * 8192;

    float bdl = INFINITY;
    int ff = 0, ll = 0;

    for (int s = 0; s < SPLIT; ++s) {
        float ms = qsA[(size_t)qidx * SPLIT + s];
        float ds = sqrtf(fmaxf(ms, 0.0f));
        if (ds == bd) {                    // exact achiever-split test
            const float4* tp = tb + (size_t)s * CHUNK;
            int jb = s * CHUNK;
            #pragma unroll 2
            for (int i = 0; i < 8; ++i) {
                int pi = i * 64 + lane;    // pair index 0..511 (lane-ascending)
                float4 A = tp[2 * pi + 0];
                float4 B = tp[2 * pi + 1];
                // point 0: x=A.x y=A.z z=B.x tt=B.z
                {
                    float u1 = __fmul_rn(q2z, B.x);
                    float u2 = __fmul_rn(q2y, A.z);
                    float a1 = __fadd_rn(u1, u2);
                    float u3 = __fmul_rn(q2x, A.x);
                    float e2 = __fadd_rn(a1, u3);
                    float ss = __fadd_rn(qq, B.z);
                    float qs = __fsub_rn(ss, e2);
                    float d  = sqrtf(fmaxf(qs, 0.0f));
                    int j = jb + 2 * pi;
                    bool lt = d < bdl, le = d <= bdl;
                    ff = lt ? j : ff; ll = le ? j : ll; bdl = fminf(bdl, d);
                }
                // point 1: x=A.y y=A.w z=B.y tt=B.w
                {
                    float u1 = __fmul_rn(q2z, B.y);
                    float u2 = __fmul_rn(q2y, A.w);
                    float a1 = __fadd_rn(u1, u2);
                    float u3 = __fmul_rn(q2x, A.y);
                    float e2 = __fadd_rn(a1, u3);
                    float ss = __fadd_rn(qq, B.w);
                    float qs = __fsub_rn(ss, e2);
                    float d  = sqrtf(fmaxf(qs, 0.0f));
                    int j = jb + 2 * pi + 1;
                    bool lt = d < bdl, le = d <= bdl;
                    ff = lt ? j : ff; ll = le ? j : ll; bdl = fminf(bdl, d);
                }
            }
        }
    }

    // 64-lane butterfly union merge (associative/commutative)
    #pragma unroll
    for (int m = 1; m < 64; m <<= 1) {
        float ob = __shfl_xor(bdl, m);
        int   of = __shfl_xor(ff, m);
        int   ol = __shfl_xor(ll, m);
        bool lt = ob < bdl, eq = ob == bdl;
        ff = lt ? of : (eq ? min(ff, of) : ff);
        ll = lt ? ol : (eq ? max(ll, ol) : ll);
        bdl = fminf(bdl, ob);
    }

    if (lane == 0) {
        int span = ll - ff;
        int idx  = (span > 1200) ? ll : ff;
        const size_t SEG = (size_t)BATCH * NPTS;
        out[2 * SEG + (size_t)dir * SEG + rem] = (float)idx;
    }
}

extern "C" void kernel_launch(void* const* d_in, const int* in_sizes, int n_in,
                              void* d_out, int out_size, void* d_ws, size_t ws_size,
                              hipStream_t stream) {
    const float* xyz1 = (const float*)d_in[0];
    const float* xyz2 = (const float*)d_in[1];
    float* out = (float*)d_out;

    char* wsp = (char*)d_ws;
    float4* pk  = (float4*)(wsp);                 // 1 MiB
    float*  qsA = (float*)(wsp + (1u << 20));     // 2 MiB
    float*  bdq = (float*)(wsp + (3u << 20));     // 256 KiB

    prep_k<<<128, 256, 0, stream>>>(xyz1, xyz2, pk);
    phaseA<<<2048, 256, 0, stream>>>(xyz1, xyz2, pk, qsA);
    mergeA<<<NQ / 256, 256, 0, stream>>>(qsA, bdq, out);
    phaseB<<<NQ / 4, 256, 0, stream>>>(xyz1, xyz2, pk, qsA, bdq, out);
}

// Round 24
// 144.985 us; speedup vs baseline: 2.7200x; 1.1041x over previous
//
#include <hip/hip_runtime.h>
#include <math.h>

// Chamfer distance, B=4, N=M=8192, fp32. Semantics validated R15-R23.
// d_out (f32): dist1[B*N] | dist2[B*M] | idx1[B*N] | idx2[B*M]
//
// Validated per-pair math (no FMA; pre-doubled q bit-exact, R22/R23-passed):
//   qq/tt = (x*x+y*y)+z*z ; e2 = (2qz*z+2qy*y)+2qx*x ; qs = (qq+tt)-e2
//   d = sqrtf(max(qs,0)) ; FIRST/LAST of min-d; idx = span>1200 ? last : first.
//
// R24: SPLIT=16 (finer achiever localization) + achiever BITMASK from
// mergeA -> phaseB scans only masked 512-point chunks (~1.0002/query),
// divergence-free ctz loop, butterfly union merge.

#define BATCH 4
#define NPTS  8192
#define NQ    65536
#define SPLIT 16
#define CHUNK 512               // points per split

// pk layout: per (src,b) slot of 8192 float4: pair p -> pk[2p]={x0,x1,y0,y1},
// pk[2p+1]={z0,z1,tt0,tt1}
__global__ __launch_bounds__(256)
void prep_k(const float* __restrict__ xyz1, const float* __restrict__ xyz2,
            float4* __restrict__ pk) {
#pragma clang fp contract(off)
    int tid = blockIdx.x * blockDim.x + threadIdx.x;   // 0..32767 pairs
    int src = tid >> 14;
    int b   = (tid >> 12) & 3;
    int p   = tid & 4095;
    const float* sp = (src == 0 ? xyz1 : xyz2) + ((size_t)b * NPTS + 2 * p) * 3;
    float x0 = sp[0], y0 = sp[1], z0 = sp[2];
    float x1 = sp[3], y1 = sp[4], z1 = sp[5];
    float t0 = __fadd_rn(__fadd_rn(__fmul_rn(x0, x0), __fmul_rn(y0, y0)), __fmul_rn(z0, z0));
    float t1 = __fadd_rn(__fadd_rn(__fmul_rn(x1, x1), __fmul_rn(y1, y1)), __fmul_rn(z1, z1));
    size_t base = (size_t)(src * 4 + b) * 8192;
    pk[base + 2 * p + 0] = make_float4(x0, x1, y0, y1);
    pk[base + 2 * p + 1] = make_float4(z0, z1, t0, t1);
}

// ---------------- Phase A: per-(query,split) min(qs) ----------------
__global__ __launch_bounds__(256)
void phaseA(const float* __restrict__ xyz1, const float* __restrict__ xyz2,
            const float4* __restrict__ pk, float* __restrict__ qsA) {
#pragma clang fp contract(off)
    int bid = blockIdx.x;                  // dir*2048 + b*512 + qw*4 + sg
    int sg  = bid & 3;
    int qw  = (bid >> 2) & 127;
    int b   = (bid >> 9) & 3;
    int dir = bid >> 11;

    int t    = threadIdx.x;
    int lane = t & 63;
    int w    = t >> 6;
    int s    = __builtin_amdgcn_readfirstlane(sg * 4 + w);   // 0..15

    int q = qw * 64 + lane;
    const float* qp = (dir == 0 ? xyz1 : xyz2) + ((size_t)b * NPTS + q) * 3;
    float qx = qp[0], qy = qp[1], qz = qp[2];
    float qq = __fadd_rn(__fadd_rn(__fmul_rn(qx, qx), __fmul_rn(qy, qy)),
                         __fmul_rn(qz, qz));
    float q2x = qx + qx, q2y = qy + qy, q2z = qz + qz;

    int tslot = (dir == 0 ? 4 : 0) + b;
    const float4* tp = pk + (size_t)tslot * 8192 + (size_t)s * (CHUNK * 2 / 2);
    // s*512 float4 entries (512 points = 256 pairs = 512 f4)

    float m0 = INFINITY, m1 = INFINITY, m2 = INFINITY, m3 = INFINITY;

    #define PQS(A, B, M)                                                    \
    {                                                                       \
        float u1a = __fmul_rn(q2z, B.x), u1b = __fmul_rn(q2z, B.y);         \
        float u2a = __fmul_rn(q2y, A.z), u2b = __fmul_rn(q2y, A.w);         \
        float a1a = __fadd_rn(u1a, u2a), a1b = __fadd_rn(u1b, u2b);         \
        float u3a = __fmul_rn(q2x, A.x), u3b = __fmul_rn(q2x, A.y);         \
        float e2a = __fadd_rn(a1a, u3a), e2b = __fadd_rn(a1b, u3b);         \
        float ssa = __fadd_rn(qq, B.z),  ssb = __fadd_rn(qq, B.w);          \
        float qsa = __fsub_rn(ssa, e2a), qsb = __fsub_rn(ssb, e2b);         \
        M = fminf(M, fminf(qsa, qsb));                                      \
    }

    #pragma unroll 2
    for (int g = 0; g < 64; ++g) {         // 4 pairs (8 points) per iter
        float4 A0 = tp[8 * g + 0], B0 = tp[8 * g + 1];
        float4 A1 = tp[8 * g + 2], B1 = tp[8 * g + 3];
        float4 A2 = tp[8 * g + 4], B2 = tp[8 * g + 5];
        float4 A3 = tp[8 * g + 6], B3 = tp[8 * g + 7];
        PQS(A0, B0, m0) PQS(A1, B1, m1) PQS(A2, B2, m2) PQS(A3, B3, m3)
    }
    #undef PQS

    float r = fminf(fminf(m0, m1), fminf(m2, m3));
    int qidx = (dir * BATCH + b) * NPTS + q;
    qsA[(size_t)qidx * SPLIT + s] = r;
}

// -------- A-merge: bd -> dist output + achiever bitmask --------
__global__ __launch_bounds__(256)
void mergeA(const float* __restrict__ qsA, unsigned* __restrict__ maskq,
            float* __restrict__ out) {
#pragma clang fp contract(off)
    int tid = blockIdx.x * blockDim.x + threadIdx.x;
    float ms[SPLIT];
    float m = INFINITY;
    #pragma unroll
    for (int s = 0; s < SPLIT; ++s) {
        ms[s] = qsA[(size_t)tid * SPLIT + s];
        m = fminf(m, ms[s]);
    }
    float bd = sqrtf(fmaxf(m, 0.0f));      // == min over d (monotone commute)

    unsigned mask = 0;
    #pragma unroll
    for (int s = 0; s < SPLIT; ++s) {
        float ds = sqrtf(fmaxf(ms[s], 0.0f));
        if (ds == bd) mask |= (1u << s);   // exact achiever-split test
    }
    maskq[tid] = mask;

    int dir = tid >> 15;
    int rem = tid & 32767;
    const size_t SEG = (size_t)BATCH * NPTS;
    out[(size_t)dir * SEG + rem] = bd;
}

// -------- Phase B: scan achiever chunks only (wave per query) --------
__global__ __launch_bounds__(256)
void phaseB(const float* __restrict__ xyz1, const float* __restrict__ xyz2,
            const float4* __restrict__ pk, const unsigned* __restrict__ maskq,
            float* __restrict__ out) {
#pragma clang fp contract(off)
    int t    = threadIdx.x;
    int w    = t >> 6;
    int lane = t & 63;
    int qidx = blockIdx.x * 4 + w;         // one wave per query
    int dir  = qidx >> 15;
    int rem  = qidx & 32767;
    int b    = rem >> 13;
    int q    = rem & (NPTS - 1);

    const float* qp = (dir == 0 ? xyz1 : xyz2) + ((size_t)b * NPTS + q) * 3;
    float qx = qp[0], qy = qp[1], qz = qp[2];
    float qq = __fadd_rn(__fadd_rn(__fmul_rn(qx, qx), __fmul_rn(qy, qy)),
                         __fmul_rn(qz, qz));
    float q2x = qx + qx, q2y = qy + qy, q2z = qz + qz;

    int tslot = (dir == 0 ? 4 : 0) + b;
    const float4* tb = pk + (size_t)tslot * 8192;

    unsigned mask = maskq[qidx];           // wave-uniform
    float bdl = INFINITY;
    int ff = 0, ll = 0;

    while (mask) {
        int s = __builtin_ctz(mask);
        mask &= mask - 1;
        const float4* tp = tb + (size_t)s * 512;   // 512 f4 = 256 pairs
        int jb = s * CHUNK;
        #pragma unroll
        for (int i = 0; i < 4; ++i) {
            int pi = i * 64 + lane;        // pair 0..255, lane-ascending
            float4 A = tp[2 * pi + 0];
            float4 B = tp[2 * pi + 1];
            // point 0: x=A.x y=A.z z=B.x tt=B.z
            {
                float u1 = __fmul_rn(q2z, B.x);
                float u2 = __fmul_rn(q2y, A.z);
                float a1 = __fadd_rn(u1, u2);
                float u3 = __fmul_rn(q2x, A.x);
                float e2 = __fadd_rn(a1, u3);
                float ss = __fadd_rn(qq, B.z);
                float qs = __fsub_rn(ss, e2);
                float d  = sqrtf(fmaxf(qs, 0.0f));
                int j = jb + 2 * pi;
                bool lt = d < bdl, le = d <= bdl;
                ff = lt ? j : ff; ll = le ? j : ll; bdl = fminf(bdl, d);
            }
            // point 1: x=A.y y=A.w z=B.y tt=B.w
            {
                float u1 = __fmul_rn(q2z, B.y);
                float u2 = __fmul_rn(q2y, A.w);
                float a1 = __fadd_rn(u1, u2);
                float u3 = __fmul_rn(q2x, A.y);
                float e2 = __fadd_rn(a1, u3);
                float ss = __fadd_rn(qq, B.w);
                float qs = __fsub_rn(ss, e2);
                float d  = sqrtf(fmaxf(qs, 0.0f));
                int j = jb + 2 * pi + 1;
                bool lt = d < bdl, le = d <= bdl;
                ff = lt ? j : ff; ll = le ? j : ll; bdl = fminf(bdl, d);
            }
        }
    }

    // 64-lane butterfly union merge (associative/commutative, validated)
    #pragma unroll
    for (int m = 1; m < 64; m <<= 1) {
        float ob = __shfl_xor(bdl, m);
        int   of = __shfl_xor(ff, m);
        int   ol = __shfl_xor(ll, m);
        bool lt = ob < bdl, eq = ob == bdl;
        ff = lt ? of : (eq ? min(ff, of) : ff);
        ll = lt ? ol : (eq ? max(ll, ol) : ll);
        bdl = fminf(bdl, ob);
    }

    if (lane == 0) {
        int span = ll - ff;
        int idx  = (span > 1200) ? ll : ff;
        const size_t SEG = (size_t)BATCH * NPTS;
        out[2 * SEG + (size_t)dir * SEG + rem] = (float)idx;
    }
}

extern "C" void kernel_launch(void* const* d_in, const int* in_sizes, int n_in,
                              void* d_out, int out_size, void* d_ws, size_t ws_size,
                              hipStream_t stream) {
    const float* xyz1 = (const float*)d_in[0];
    const float* xyz2 = (const float*)d_in[1];
    float* out = (float*)d_out;

    char* wsp = (char*)d_ws;
    float4*   pk    = (float4*)(wsp);                 // 1 MiB
    float*    qsA   = (float*)(wsp + (1u << 20));     // 4 MiB
    unsigned* maskq = (unsigned*)(wsp + (5u << 20));  // 256 KiB

    prep_k<<<128, 256, 0, stream>>>(xyz1, xyz2, pk);
    phaseA<<<4096, 256, 0, stream>>>(xyz1, xyz2, pk, qsA);
    mergeA<<<NQ / 256, 256, 0, stream>>>(qsA, maskq, out);
    phaseB<<<NQ / 4, 256, 0, stream>>>(xyz1, xyz2, pk, maskq, out);
}

// Round 25
// 118.569 us; speedup vs baseline: 3.3260x; 1.2228x over previous
//
#include <hip/hip_runtime.h>
#include <math.h>

// Chamfer distance, B=4, N=M=8192, fp32. Semantics validated R15-R24.
// d_out (f32): dist1[B*N] | dist2[B*M] | idx1[B*N] | idx2[B*M]
//
// Validated per-pair math (no FMA; pre-doubled q bit-exact, R22-R24 passed):
//   qq/tt = (x*x+y*y)+z*z ; e2 = (2qz*z+2qy*y)+2qx*x ; qs = (qq+tt)-e2
//   d = sqrtf(max(qs,0)) ; FIRST/LAST of min-d; idx = span>1200 ? last : first.
//
// R25 = R24 (SPLIT=16, achiever bitmask, ctz phaseB) with phaseA's packed
// f2 ext_vector math restored (R23 form -> v_pk_mul/add_f32; R24's scalar
// rewrite was a 63->107us regression).

#define BATCH 4
#define NPTS  8192
#define NQ    65536
#define SPLIT 16
#define CHUNK 512               // points per split

typedef float f2 __attribute__((ext_vector_type(2)));

// pk layout: per (src,b) slot of 8192 float4: pair p -> pk[2p]={x0,x1,y0,y1},
// pk[2p+1]={z0,z1,tt0,tt1}
__global__ __launch_bounds__(256)
void prep_k(const float* __restrict__ xyz1, const float* __restrict__ xyz2,
            float4* __restrict__ pk) {
#pragma clang fp contract(off)
    int tid = blockIdx.x * blockDim.x + threadIdx.x;   // 0..32767 pairs
    int src = tid >> 14;
    int b   = (tid >> 12) & 3;
    int p   = tid & 4095;
    const float* sp = (src == 0 ? xyz1 : xyz2) + ((size_t)b * NPTS + 2 * p) * 3;
    float x0 = sp[0], y0 = sp[1], z0 = sp[2];
    float x1 = sp[3], y1 = sp[4], z1 = sp[5];
    float t0 = __fadd_rn(__fadd_rn(__fmul_rn(x0, x0), __fmul_rn(y0, y0)), __fmul_rn(z0, z0));
    float t1 = __fadd_rn(__fadd_rn(__fmul_rn(x1, x1), __fmul_rn(y1, y1)), __fmul_rn(z1, z1));
    size_t base = (size_t)(src * 4 + b) * 8192;
    pk[base + 2 * p + 0] = make_float4(x0, x1, y0, y1);
    pk[base + 2 * p + 1] = make_float4(z0, z1, t0, t1);
}

// ---------------- Phase A: per-(query,split) min(qs), packed math ----------------
__global__ __launch_bounds__(256)
void phaseA(const float* __restrict__ xyz1, const float* __restrict__ xyz2,
            const float4* __restrict__ pk, float* __restrict__ qsA) {
#pragma clang fp contract(off)
    int bid = blockIdx.x;                  // dir*2048 + b*512 + qw*4 + sg
    int sg  = bid & 3;
    int qw  = (bid >> 2) & 127;
    int b   = (bid >> 9) & 3;
    int dir = bid >> 11;

    int t    = threadIdx.x;
    int lane = t & 63;
    int w    = t >> 6;
    int s    = __builtin_amdgcn_readfirstlane(sg * 4 + w);   // 0..15

    int q = qw * 64 + lane;
    const float* qp = (dir == 0 ? xyz1 : xyz2) + ((size_t)b * NPTS + q) * 3;
    float qx = qp[0], qy = qp[1], qz = qp[2];
    float qq = __fadd_rn(__fadd_rn(__fmul_rn(qx, qx), __fmul_rn(qy, qy)),
                         __fmul_rn(qz, qz));
    f2 Q2X = {qx + qx, qx + qx};
    f2 Q2Y = {qy + qy, qy + qy};
    f2 Q2Z = {qz + qz, qz + qz};
    f2 QQ  = {qq, qq};

    int tslot = (dir == 0 ? 4 : 0) + b;
    const float4* tp = pk + (size_t)tslot * 8192 + (size_t)s * 512;  // 512 f4

    f2 m0 = {INFINITY, INFINITY}, m1 = m0, m2 = m0, m3 = m0;

    #define PQS(A, B, M)                                                    \
    {                                                                       \
        f2 X = {A.x, A.y}, Y = {A.z, A.w}, Z = {B.x, B.y}, T = {B.z, B.w};  \
        f2 u1 = Q2Z * Z;                                                    \
        f2 u2 = Q2Y * Y;                                                    \
        f2 a1 = u1 + u2;                                                    \
        f2 u3 = Q2X * X;                                                    \
        f2 e2 = a1 + u3;                                                    \
        f2 ss = QQ + T;                                                     \
        f2 qs = ss - e2;                                                    \
        M.x = fminf(M.x, qs.x);                                             \
        M.y = fminf(M.y, qs.y);                                             \
    }

    #pragma unroll 2
    for (int g = 0; g < 64; ++g) {         // 4 pairs (8 points) per iter
        float4 A0 = tp[8 * g + 0], B0 = tp[8 * g + 1];
        float4 A1 = tp[8 * g + 2], B1 = tp[8 * g + 3];
        float4 A2 = tp[8 * g + 4], B2 = tp[8 * g + 5];
        float4 A3 = tp[8 * g + 6], B3 = tp[8 * g + 7];
        PQS(A0, B0, m0) PQS(A1, B1, m1) PQS(A2, B2, m2) PQS(A3, B3, m3)
    }
    #undef PQS

    float r = fminf(fminf(fminf(m0.x, m0.y), fminf(m1.x, m1.y)),
                    fminf(fminf(m2.x, m2.y), fminf(m3.x, m3.y)));
    int qidx = (dir * BATCH + b) * NPTS + q;
    qsA[(size_t)qidx * SPLIT + s] = r;
}

// -------- A-merge: bd -> dist output + achiever bitmask --------
__global__ __launch_bounds__(256)
void mergeA(const float* __restrict__ qsA, unsigned* __restrict__ maskq,
            float* __restrict__ out) {
#pragma clang fp contract(off)
    int tid = blockIdx.x * blockDim.x + threadIdx.x;
    float ms[SPLIT];
    float m = INFINITY;
    #pragma unroll
    for (int s = 0; s < SPLIT; ++s) {
        ms[s] = qsA[(size_t)tid * SPLIT + s];
        m = fminf(m, ms[s]);
    }
    float bd = sqrtf(fmaxf(m, 0.0f));      // == min over d (monotone commute)

    unsigned mask = 0;
    #pragma unroll
    for (int s = 0; s < SPLIT; ++s) {
        float ds = sqrtf(fmaxf(ms[s], 0.0f));
        if (ds == bd) mask |= (1u << s);   // exact achiever-split test
    }
    maskq[tid] = mask;

    int dir = tid >> 15;
    int rem = tid & 32767;
    const size_t SEG = (size_t)BATCH * NPTS;
    out[(size_t)dir * SEG + rem] = bd;
}

// -------- Phase B: scan achiever chunks only (wave per query) --------
__global__ __launch_bounds__(256)
void phaseB(const float* __restrict__ xyz1, const float* __restrict__ xyz2,
            const float4* __restrict__ pk, const unsigned* __restrict__ maskq,
            float* __restrict__ out) {
#pragma clang fp contract(off)
    int t    = threadIdx.x;
    int w    = t >> 6;
    int lane = t & 63;
    int qidx = blockIdx.x * 4 + w;         // one wave per query
    int dir  = qidx >> 15;
    int rem  = qidx & 32767;
    int b    = rem >> 13;
    int q    = rem & (NPTS - 1);

    const float* qp = (dir == 0 ? xyz1 : xyz2) + ((size_t)b * NPTS + q) * 3;
    float qx = qp[0], qy = qp[1], qz = qp[2];
    float qq = __fadd_rn(__fadd_rn(__fmul_rn(qx, qx), __fmul_rn(qy, qy)),
                         __fmul_rn(qz, qz));
    float q2x = qx + qx, q2y = qy + qy, q2z = qz + qz;

    int tslot = (dir == 0 ? 4 : 0) + b;
    const float4* tb = pk + (size_t)tslot * 8192;

    unsigned mask = maskq[qidx];           // wave-uniform
    float bdl = INFINITY;
    int ff = 0, ll = 0;

    while (mask) {
        int s = __builtin_ctz(mask);
        mask &= mask - 1;
        const float4* tp = tb + (size_t)s * 512;   // 512 f4 = 256 pairs
        int jb = s * CHUNK;
        #pragma unroll
        for (int i = 0; i < 4; ++i) {
            int pi = i * 64 + lane;        // pair 0..255, lane-ascending
            float4 A = tp[2 * pi + 0];
            float4 B = tp[2 * pi + 1];
            // point 0: x=A.x y=A.z z=B.x tt=B.z
            {
                float u1 = __fmul_rn(q2z, B.x);
                float u2 = __fmul_rn(q2y, A.z);
                float a1 = __fadd_rn(u1, u2);
                float u3 = __fmul_rn(q2x, A.x);
                float e2 = __fadd_rn(a1, u3);
                float ss = __fadd_rn(qq, B.z);
                float qs = __fsub_rn(ss, e2);
                float d  = sqrtf(fmaxf(qs, 0.0f));
                int j = jb + 2 * pi;
                bool lt = d < bdl, le = d <= bdl;
                ff = lt ? j : ff; ll = le ? j : ll; bdl = fminf(bdl, d);
            }
            // point 1: x=A.y y=A.w z=B.y tt=B.w
            {
                float u1 = __fmul_rn(q2z, B.y);
                float u2 = __fmul_rn(q2y, A.w);
                float a1 = __fadd_rn(u1, u2);
                float u3 = __fmul_rn(q2x, A.y);
                float e2 = __fadd_rn(a1, u3);
                float ss = __fadd_rn(qq, B.w);
                float qs = __fsub_rn(ss, e2);
                float d  = sqrtf(fmaxf(qs, 0.0f));
                int j = jb + 2 * pi + 1;
                bool lt = d < bdl, le = d <= bdl;
                ff = lt ? j : ff; ll = le ? j : ll; bdl = fminf(bdl, d);
            }
        }
    }

    // 64-lane butterfly union merge (associative/commutative, validated)
    #pragma unroll
    for (int m = 1; m < 64; m <<= 1) {
        float ob = __shfl_xor(bdl, m);
        int   of = __shfl_xor(ff, m);
        int   ol = __shfl_xor(ll, m);
        bool lt = ob < bdl, eq = ob == bdl;
        ff = lt ? of : (eq ? min(ff, of) : ff);
        ll = lt ? ol : (eq ? max(ll, ol) : ll);
        bdl = fminf(bdl, ob);
    }

    if (lane == 0) {
        int span = ll - ff;
        int idx  = (span > 1200) ? ll : ff;
        const size_t SEG = (size_t)BATCH * NPTS;
        out[2 * SEG + (size_t)dir * SEG + rem] = (float)idx;
    }
}

extern "C" void kernel_launch(void* const* d_in, const int* in_sizes, int n_in,
                              void* d_out, int out_size, void* d_ws, size_t ws_size,
                              hipStream_t stream) {
    const float* xyz1 = (const float*)d_in[0];
    const float* xyz2 = (const float*)d_in[1];
    float* out = (float*)d_out;

    char* wsp = (char*)d_ws;
    float4*   pk    = (float4*)(wsp);                 // 1 MiB
    float*    qsA   = (float*)(wsp + (1u << 20));     // 4 MiB
    unsigned* maskq = (unsigned*)(wsp + (5u << 20));  // 256 KiB

    prep_k<<<128, 256, 0, stream>>>(xyz1, xyz2, pk);
    phaseA<<<4096, 256, 0, stream>>>(xyz1, xyz2, pk, qsA);
    mergeA<<<NQ / 256, 256, 0, stream>>>(qsA, maskq, out);
    phaseB<<<NQ / 4, 256, 0, stream>>>(xyz1, xyz2, pk, maskq, out);
}